// Round 9
// baseline (255.750 us; speedup 1.0000x reference)
//
#include <hip/hip_runtime.h>

// Problem constants (B=32, N=256, D=256 -> M=8192)
#define M_ROWS 8192
#define D_DIM  256
#define BM     256                // block tile rows (8 waves x 32)
#define BN     128                // block tile cols
#define NBI    (M_ROWS / BM)      // 32 i-tiles
#define NBJ    (M_ROWS / BN)      // 64 j-tiles
#define NJOBS  (NBI * NBJ)        // 2048 gemm blocks

// Fold 1/TEMP * log2(e) into normalization: acc = log2(e)*sim/TEMP, e = exp2(acc)
#define ALPHA  4.53982478f        // sqrt(log2(e)/0.07)

// fp8 fragment layout for mfma_scale_f32_16x16x128_f8f6f4 (K=128 per MFMA):
//   tile16 = 16 rows x 256 k = 4 KB, at tile*4096
//   per k-step s (0/1, K=128 each): 2 KB chunk at +s*2048
//   within chunk: half h (0/1) at +h*1024, then lane*16 bytes
//   lane l holds row (l&15), k = s*128 + (l>>4)*32 + h*16 + byte(0..15)
// => every load/store/ds op is 64 lanes x 16 B fully contiguous (stride-16).

typedef __attribute__((ext_vector_type(4))) float floatx4;  // MFMA C/D
typedef __attribute__((ext_vector_type(2))) float floatx2;  // packed f32 pair
typedef __attribute__((ext_vector_type(8))) int   intx8;    // MFMA A/B (32 B fp8)

__device__ inline float fast_exp2(float x) {
#if __has_builtin(__builtin_amdgcn_exp2f)
    return __builtin_amdgcn_exp2f(x);
#else
    return exp2f(x);
#endif
}

// MX-scaled fp8 MFMA with unit scales (E8M0 bias 127 -> 2^0). cbsz/blgp = 0 = OCP e4m3.
__device__ inline floatx4 mfma_fp8(intx8 a, intx8 b, floatx4 c) {
    return __builtin_amdgcn_mfma_scale_f32_16x16x128_f8f6f4(
        a, b, c, 0, 0, 0, 0x7f7f7f7f, 0, 0x7f7f7f7f);
}

// Kernel 1: L2-normalize, scale by ALPHA, emit fp8 e4m3 in fragment order.
// Each thread loads exactly the 16 f32 it emits (64 B contiguous); only the
// row-norm is cross-thread (2 shuffles + tiny LDS). Output store = dst + t*16,
// fully coalesced. Block 0 zeroes the finalize accumulators.
__global__ __launch_bounds__(256) void normalize_kernel(
    const float* __restrict__ af, const float* __restrict__ vf,
    unsigned char* __restrict__ aB, unsigned char* __restrict__ vB,
    float* __restrict__ glob)
{
    __shared__ float ssb[16][4];

    if (blockIdx.x == 0) {
        if (threadIdx.x < 4) glob[threadIdx.x] = 0.f;
        if (threadIdx.x == 4) ((int*)glob)[4] = 0;
    }

    const int b = blockIdx.x;            // 0..1023
    const bool isA = b < 512;
    const int T = isA ? b : b - 512;     // tile16 index 0..511
    const float* src = (isA ? af : vf) + (size_t)T * 16 * D_DIM;
    unsigned char* dst = (isA ? aB : vB) + (size_t)T * 4096;

    const int t    = threadIdx.x;
    const int wave = t >> 6, lane = t & 63;
    const int row  = t & 15;             // == lane & 15
    const int kq   = (t >> 4) & 3;
    const int h    = (t >> 6) & 1;
    const int s    = t >> 7;
    const int kbase = s * 128 + kq * 32 + h * 16;

    const float* p = src + row * D_DIM + kbase;
    float4 x0 = ((const float4*)p)[0], x1 = ((const float4*)p)[1];
    float4 x2 = ((const float4*)p)[2], x3 = ((const float4*)p)[3];

    float ss = x0.x*x0.x + x0.y*x0.y + x0.z*x0.z + x0.w*x0.w
             + x1.x*x1.x + x1.y*x1.y + x1.z*x1.z + x1.w*x1.w
             + x2.x*x2.x + x2.y*x2.y + x2.z*x2.z + x2.w*x2.w
             + x3.x*x3.x + x3.y*x3.y + x3.z*x3.z + x3.w*x3.w;
    // within a wave, lanes differing in bits 4..5 are the 4 kq groups of this row
    ss += __shfl_xor(ss, 16, 64);
    ss += __shfl_xor(ss, 32, 64);
    if (lane < 16) ssb[lane][wave] = ss;
    __syncthreads();
    float tot = ssb[row][0] + ssb[row][1] + ssb[row][2] + ssb[row][3];
    float scale = ALPHA / fmaxf(sqrtf(tot), 1e-12f);

    int4 o;
    int pk;
    pk  = __builtin_amdgcn_cvt_pk_fp8_f32(x0.x*scale, x0.y*scale, 0, false);
    pk  = __builtin_amdgcn_cvt_pk_fp8_f32(x0.z*scale, x0.w*scale, pk, true);
    o.x = pk;
    pk  = __builtin_amdgcn_cvt_pk_fp8_f32(x1.x*scale, x1.y*scale, 0, false);
    pk  = __builtin_amdgcn_cvt_pk_fp8_f32(x1.z*scale, x1.w*scale, pk, true);
    o.y = pk;
    pk  = __builtin_amdgcn_cvt_pk_fp8_f32(x2.x*scale, x2.y*scale, 0, false);
    pk  = __builtin_amdgcn_cvt_pk_fp8_f32(x2.z*scale, x2.w*scale, pk, true);
    o.z = pk;
    pk  = __builtin_amdgcn_cvt_pk_fp8_f32(x3.x*scale, x3.y*scale, 0, false);
    pk  = __builtin_amdgcn_cvt_pk_fp8_f32(x3.z*scale, x3.w*scale, pk, true);
    o.w = pk;
    *(int4*)(dst + (size_t)t * 16) = o;
}

// Kernel 2: fused GEMM (acc = log2e*sim/T) via MX-scaled fp8 K=128 MFMA.
// R3's proven skeleton (block 256x128, 8 waves, reg-staged B tile in LDS,
// flat single compute region) + R6's proven epilogue (packed v_pk_fma_f32
// (tot,class1) accumulate, LDS-transpose row reduction over the dead B tile).
// NO mid-kernel staging / multi-buffer (scratch-bombs: R4/R7/R8).
__global__ __launch_bounds__(512, 4) void gemm_loss_kernel(
    const unsigned char* __restrict__ aB, const unsigned char* __restrict__ vB,
    const int* __restrict__ la, const int* __restrict__ lv,
    float* __restrict__ rowPart, float* __restrict__ colPart)
{
    __shared__ __align__(16) unsigned char ldsB[32768]; // B tile; later rp[256][16] floatx2
    __shared__ floatx2 colbuf[8][BN];                   // [wave][col] (tot,c1) = 8 KB

    const int tid  = threadIdx.x;
    const int wave = tid >> 6, lane = tid & 63;
    const int quad = lane >> 4, l16 = lane & 15;

    // supertile swizzle: 8 supers x 256 inner -> 16x16 tile regions (L2 locality)
    const int super = blockIdx.x >> 8;          // 0..7
    const int inner = blockIdx.x & 255;
    const int bx = (super & 1) * 16 + (inner & 15);    // 0..31 (i-tile of 256 rows)
    const int by = (super >> 1) * 16 + (inner >> 4);   // 0..63 (j-tile of 128 cols)
    const int i0 = bx * BM, j0 = by * BN;

    // ---- stage B tile into LDS (layout == global fragment layout, stride-16)
    {
        const unsigned char* vsrc = vB + (size_t)by * 32768 + (size_t)tid * 16;
        unsigned char* ldst = ldsB + tid * 16;
        #pragma unroll
        for (int c = 0; c < 4; ++c)
            *(int4*)(ldst + c * 8192) = *(const int4*)(vsrc + c * 8192);
    }

    // ---- A fragments [it][s]: 32 B each, halves at +0 / +1024
    const unsigned char* Abase = aB + (size_t)(bx * 16 + wave * 2) * 4096
                                    + (size_t)lane * 16;
    intx8 afr[2][2];
    #pragma unroll
    for (int it = 0; it < 2; ++it) {
        #pragma unroll
        for (int s = 0; s < 2; ++s) {
            int4 h0 = *(const int4*)(Abase + it * 4096 + s * 2048);
            int4 h1 = *(const int4*)(Abase + it * 4096 + s * 2048 + 1024);
            afr[it][s] = intx8{h0.x, h0.y, h0.z, h0.w, h1.x, h1.y, h1.z, h1.w};
        }
    }

    __syncthreads();

    // ---- main loop: 2 k-steps x 8 j-tiles, 2 MFMAs per B fragment
    floatx4 acc[2][8] = {};
    const unsigned char* Bl = ldsB + lane * 16;
    #pragma unroll
    for (int s = 0; s < 2; ++s) {
        #pragma unroll
        for (int jt = 0; jt < 8; ++jt) {
            int4 h0 = *(const int4*)(Bl + jt * 4096 + s * 2048);
            int4 h1 = *(const int4*)(Bl + jt * 4096 + s * 2048 + 1024);
            intx8 bf = intx8{h0.x, h0.y, h0.z, h0.w, h1.x, h1.y, h1.z, h1.w};
            acc[0][jt] = mfma_fp8(afr[0][s], bf, acc[0][jt]);
            acc[1][jt] = mfma_fp8(afr[1][s], bf, acc[1][jt]);
        }
    }

    // ---- labels (after MFMA loop: afr dies there, keeps peak VGPR low)
    const int baseRow = i0 + wave * 32;
    floatx2 ma2[2][4];
    #pragma unroll
    for (int it = 0; it < 2; ++it)
        #pragma unroll
        for (int r = 0; r < 4; ++r)
            ma2[it][r] = floatx2{1.f, (float)la[baseRow + it * 16 + quad * 4 + r]};

    // ---- epilogue: exp2 + packed accumulate; C/D: col = l16, row = quad*4+r
    floatx2 rowacc[2][4] = {};
    #pragma unroll
    for (int jt = 0; jt < 8; ++jt) {
        floatx2 mj = floatx2{1.f, (float)lv[j0 + jt * 16 + l16]};
        floatx2 ca = {};
        #pragma unroll
        for (int it = 0; it < 2; ++it) {
            #pragma unroll
            for (int r = 0; r < 4; ++r) {
                float e = fast_exp2(acc[it][jt][r]);
                floatx2 e2 = {e, e};
                rowacc[it][r] = e2 * mj + rowacc[it][r];    // v_pk_fma_f32
                ca = e2 * ma2[it][r] + ca;                  // v_pk_fma_f32
            }
        }
        // col partial: reduce over quads within wave (register-only)
        ca.x += __shfl_xor(ca.x, 16, 64); ca.y += __shfl_xor(ca.y, 16, 64);
        ca.x += __shfl_xor(ca.x, 32, 64); ca.y += __shfl_xor(ca.y, 32, 64);
        if (quad == 0) colbuf[wave][jt * 16 + l16] = ca;
    }

    __syncthreads();    // all waves done reading ldsB -> safe to alias as rp

    // ---- row partials -> LDS transpose buffer rp[row 0..255][slot = l16]
    floatx2* rp = (floatx2*)ldsB;                       // 256*16*8 = 32768 B exact
    #pragma unroll
    for (int it = 0; it < 2; ++it)
        #pragma unroll
        for (int r = 0; r < 4; ++r)
            rp[(wave * 32 + it * 16 + quad * 4 + r) * 16 + l16] = rowacc[it][r];
    __syncthreads();

    // ---- final sums + coalesced global writes
    {
        const int row = tid >> 1, h = tid & 1;      // 2 threads per row (256 rows)
        const float4* b4 = (const float4*)(rp + (size_t)row * 16 + h * 8);
        float4 q0 = b4[0], q1 = b4[1], q2 = b4[2], q3 = b4[3];
        floatx2 s = floatx2{q0.x, q0.y} + floatx2{q0.z, q0.w}
                  + floatx2{q1.x, q1.y} + floatx2{q1.z, q1.w}
                  + floatx2{q2.x, q2.y} + floatx2{q2.z, q2.w}
                  + floatx2{q3.x, q3.y} + floatx2{q3.z, q3.w};
        s.x += __shfl_xor(s.x, 1, 64);
        s.y += __shfl_xor(s.y, 1, 64);
        if (h == 0)
            *(floatx2*)&rowPart[((size_t)by * M_ROWS + i0 + row) * 2] = s;

        if (tid < BN) {
            floatx2 c = colbuf[0][tid] + colbuf[1][tid] + colbuf[2][tid]
                      + colbuf[3][tid] + colbuf[4][tid] + colbuf[5][tid]
                      + colbuf[6][tid] + colbuf[7][tid];
            *(floatx2*)&colPart[((size_t)bx * M_ROWS + j0 + tid) * 2] = c;
        }
    }
}

// Kernel 3: reduce partials (64 row-slabs / 32 col-slabs), per-row/col log
// terms, then merged finalize: per-block (sum,count) -> device atomicAdd; last
// block (atomic counter) computes the final scalar. Blocks 0..31 = rows,
// 32..63 = cols. glob: [sumA, cntA, sumV, cntV, (int)counter].
__global__ __launch_bounds__(256) void reduce_kernel(
    const float* __restrict__ rowPart, const float* __restrict__ colPart,
    const int* __restrict__ la, const int* __restrict__ lv,
    float* __restrict__ glob, float* __restrict__ out)
{
    const int bid = blockIdx.x;
    const bool aside = bid < 32;
    const int idx = (aside ? bid : bid - 32) * 256 + threadIdx.x;   // row or col index
    const float* part = aside ? rowPart : colPart;
    const int* lab = aside ? la : lv;
    const int nslab = aside ? 64 : 32;

    float tot = 0.f, c1 = 0.f;
    #pragma unroll 4
    for (int b = 0; b < nslab; ++b) {
        float2 p = *(const float2*)(part + ((size_t)b * M_ROWS + idx) * 2);
        tot += p.x; c1 += p.y;
    }
    float num = lab[idx] ? c1 : 0.1f * (tot - c1);
    float lg = 0.f, cnt = 0.f;
    if (num > 0.f) { lg = logf((num + 1e-8f) / (tot + 1e-8f)); cnt = 1.f; }

    #pragma unroll
    for (int m = 1; m < 64; m <<= 1) {
        lg  += __shfl_xor(lg,  m, 64);
        cnt += __shfl_xor(cnt, m, 64);
    }
    __shared__ float red[4][2];
    const int w = threadIdx.x >> 6, ln = threadIdx.x & 63;
    if (ln == 0) { red[w][0] = lg; red[w][1] = cnt; }
    __syncthreads();
    if (threadIdx.x == 0) {
        float slg  = red[0][0] + red[1][0] + red[2][0] + red[3][0];
        float scnt = red[0][1] + red[1][1] + red[2][1] + red[3][1];
        float* base = glob + (aside ? 0 : 2);
        atomicAdd(&base[0], slg);
        atomicAdd(&base[1], scnt);
        __threadfence();
        int old = atomicAdd((int*)glob + 4, 1);
        if (old == 63) {
            __threadfence();
            float sA = atomicAdd(&glob[0], 0.f);
            float cA = atomicAdd(&glob[1], 0.f);
            float sV = atomicAdd(&glob[2], 0.f);
            float cV = atomicAdd(&glob[3], 0.f);
            float lossA = -sA / fmaxf(cA, 1.f);
            float lossV = -sV / fmaxf(cV, 1.f);
            out[0] = 0.5f * (lossA + lossV);
        }
    }
}

extern "C" void kernel_launch(void* const* d_in, const int* in_sizes, int n_in,
                              void* d_out, int out_size, void* d_ws, size_t ws_size,
                              hipStream_t stream)
{
    const float* af = (const float*)d_in[0];
    const float* vf = (const float*)d_in[1];
    const int*   la = (const int*)d_in[2];
    const int*   lv = (const int*)d_in[3];
    float* out = (float*)d_out;

    char* ws = (char*)d_ws;
    unsigned char* aB = (unsigned char*)ws;                            // 2 MiB (fp8 fragment order)
    unsigned char* vB = (unsigned char*)(ws + 2ull * 1024 * 1024);     // 2 MiB
    float* rowPart   = (float*)(ws +  4ull * 1024 * 1024);             // 4 MiB [64][8192][2]
    float* colPart   = (float*)(ws +  8ull * 1024 * 1024);             // 2 MiB [32][8192][2]
    float* glob      = (float*)(ws + 12ull * 1024 * 1024);             // 4 floats + counter

    normalize_kernel<<<1024, 256, 0, stream>>>(af, vf, aB, vB, glob);
    gemm_loss_kernel<<<NJOBS, 512, 0, stream>>>(aB, vB, la, lv, rowPart, colPart);
    reduce_kernel<<<64, 256, 0, stream>>>(rowPart, colPart, la, lv, glob, out);
}

// Round 10
// 129.328 us; speedup vs baseline: 1.9775x; 1.9775x over previous
//
#include <hip/hip_runtime.h>

// Problem constants (B=32, N=256, D=256 -> M=8192)
#define M_ROWS 8192
#define D_DIM  256
#define BM     128                // block tile rows (4 waves x 32)
#define NBI    (M_ROWS / BM)      // 64 i-tiles
#define JGRP   16                 // j-groups; each block sweeps 512 cols
#define NJOBS  (NBI * JGRP)       // 1024 gemm blocks

// Fold 1/TEMP * log2(e) into normalization: acc = log2(e)*sim/TEMP, e = exp2(acc)
#define ALPHA  4.53982478f        // sqrt(log2(e)/0.07)

// fp8 fragment layout for mfma_scale_f32_16x16x128_f8f6f4 (K=128 per MFMA):
//   tile16 = 16 rows x 256 k = 4 KB, at tile*4096
//   per k-step s (0/1, K=128 each): 2 KB chunk at +s*2048
//   within chunk: half h (0/1) at +h*1024, then lane*16 bytes
//   lane l holds row (l&15), k = s*128 + (l>>4)*32 + h*16 + byte(0..15)
// => every B-fragment read is 64 lanes x 16 B fully contiguous (1 KB
//    global_load_dwordx4) -- B is consumed straight from L2, no LDS staging.

typedef __attribute__((ext_vector_type(4))) float floatx4;  // MFMA C/D
typedef __attribute__((ext_vector_type(2))) float floatx2;  // packed f32 pair
typedef __attribute__((ext_vector_type(8))) int   intx8;    // MFMA A/B (32 B fp8)

__device__ inline float fast_exp2(float x) {
#if __has_builtin(__builtin_amdgcn_exp2f)
    return __builtin_amdgcn_exp2f(x);
#else
    return exp2f(x);
#endif
}

// MX-scaled fp8 MFMA with unit scales (E8M0 bias 127 -> 2^0). cbsz/blgp = 0 = OCP e4m3.
__device__ inline floatx4 mfma_fp8(intx8 a, intx8 b, floatx4 c) {
    return __builtin_amdgcn_mfma_scale_f32_16x16x128_f8f6f4(
        a, b, c, 0, 0, 0, 0x7f7f7f7f, 0, 0x7f7f7f7f);
}

// Kernel 1: L2-normalize, scale by ALPHA, emit fp8 e4m3 in fragment order.
// Each thread loads exactly the 16 f32 it emits (64 B contiguous); only the
// row-norm is cross-thread (2 shuffles + tiny LDS). Output store = dst + t*16,
// fully coalesced. Block 0 zeroes the finalize accumulators.
__global__ __launch_bounds__(256) void normalize_kernel(
    const float* __restrict__ af, const float* __restrict__ vf,
    unsigned char* __restrict__ aB, unsigned char* __restrict__ vB,
    float* __restrict__ glob)
{
    __shared__ float ssb[16][4];

    if (blockIdx.x == 0) {
        if (threadIdx.x < 4) glob[threadIdx.x] = 0.f;
        if (threadIdx.x == 4) ((int*)glob)[4] = 0;
    }

    const int b = blockIdx.x;            // 0..1023
    const bool isA = b < 512;
    const int T = isA ? b : b - 512;     // tile16 index 0..511
    const float* src = (isA ? af : vf) + (size_t)T * 16 * D_DIM;
    unsigned char* dst = (isA ? aB : vB) + (size_t)T * 4096;

    const int t    = threadIdx.x;
    const int wave = t >> 6, lane = t & 63;
    const int row  = t & 15;             // == lane & 15
    const int kq   = (t >> 4) & 3;
    const int h    = (t >> 6) & 1;
    const int s    = t >> 7;
    const int kbase = s * 128 + kq * 32 + h * 16;

    const float* p = src + row * D_DIM + kbase;
    float4 x0 = ((const float4*)p)[0], x1 = ((const float4*)p)[1];
    float4 x2 = ((const float4*)p)[2], x3 = ((const float4*)p)[3];

    float ss = x0.x*x0.x + x0.y*x0.y + x0.z*x0.z + x0.w*x0.w
             + x1.x*x1.x + x1.y*x1.y + x1.z*x1.z + x1.w*x1.w
             + x2.x*x2.x + x2.y*x2.y + x2.z*x2.z + x2.w*x2.w
             + x3.x*x3.x + x3.y*x3.y + x3.z*x3.z + x3.w*x3.w;
    // within a wave, lanes differing in bits 4..5 are the 4 kq groups of this row
    ss += __shfl_xor(ss, 16, 64);
    ss += __shfl_xor(ss, 32, 64);
    if (lane < 16) ssb[lane][wave] = ss;
    __syncthreads();
    float tot = ssb[row][0] + ssb[row][1] + ssb[row][2] + ssb[row][3];
    float scale = ALPHA / fmaxf(sqrtf(tot), 1e-12f);

    int4 o;
    int pk;
    pk  = __builtin_amdgcn_cvt_pk_fp8_f32(x0.x*scale, x0.y*scale, 0, false);
    pk  = __builtin_amdgcn_cvt_pk_fp8_f32(x0.z*scale, x0.w*scale, pk, true);
    o.x = pk;
    pk  = __builtin_amdgcn_cvt_pk_fp8_f32(x1.x*scale, x1.y*scale, 0, false);
    pk  = __builtin_amdgcn_cvt_pk_fp8_f32(x1.z*scale, x1.w*scale, pk, true);
    o.y = pk;
    pk  = __builtin_amdgcn_cvt_pk_fp8_f32(x2.x*scale, x2.y*scale, 0, false);
    pk  = __builtin_amdgcn_cvt_pk_fp8_f32(x2.z*scale, x2.w*scale, pk, true);
    o.z = pk;
    pk  = __builtin_amdgcn_cvt_pk_fp8_f32(x3.x*scale, x3.y*scale, 0, false);
    pk  = __builtin_amdgcn_cvt_pk_fp8_f32(x3.z*scale, x3.w*scale, pk, true);
    o.w = pk;
    *(int4*)(dst + (size_t)t * 16) = o;
}

// Kernel 2: fused GEMM (acc = log2e*sim/T) via MX-scaled fp8 K=128 MFMA,
// exp2 + packed (tot,class1) sums. Block = 128 rows x 512-col j-group, 4
// waves. B fragments read DIRECTLY from L2 (coalesced 1 KB loads; no LDS
// staging, no barriers in the j-loop). A frags / labels / rowacc amortized
// over 64K outputs. Col partials -> wave-private global slabs (no atomics).
// LDS 16 KB (row-transpose only). NO __launch_bounds__ occupancy floor:
// the forced-VGPR-cap spill bombs (R4/R7/R8/R9) all came from one.
__global__ __launch_bounds__(256) void gemm_loss_kernel(
    const unsigned char* __restrict__ aB, const unsigned char* __restrict__ vB,
    const int* __restrict__ la, const int* __restrict__ lv,
    float* __restrict__ rowPart, float* __restrict__ colPartW)
{
    __shared__ __align__(16) floatx2 rp[BM * 16];   // 16 KB row-transpose buffer

    const int tid  = threadIdx.x;
    const int wave = tid >> 6, lane = tid & 63;
    const int quad = lane >> 4, l16 = lane & 15;

    const int bx = blockIdx.x & 63;             // i-tile (128 rows)
    const int jg = blockIdx.x >> 6;             // j-group (512 cols)
    const int i0 = bx * BM, j0 = jg * 512;

    // ---- A fragments [it][s]: 32 B each, halves at +0 / +1024 (once per block)
    const unsigned char* Abase = aB + (size_t)(bx * 8 + wave * 2) * 4096
                                    + (size_t)lane * 16;
    intx8 afr[2][2];
    #pragma unroll
    for (int it = 0; it < 2; ++it) {
        #pragma unroll
        for (int s = 0; s < 2; ++s) {
            int4 h0 = *(const int4*)(Abase + it * 4096 + s * 2048);
            int4 h1 = *(const int4*)(Abase + it * 4096 + s * 2048 + 1024);
            afr[it][s] = intx8{h0.x, h0.y, h0.z, h0.w, h1.x, h1.y, h1.z, h1.w};
        }
    }

    // ---- row labels as packed (1, label), once per block
    const int baseRow = i0 + wave * 32;
    floatx2 ma2[2][4];
    #pragma unroll
    for (int it = 0; it < 2; ++it)
        #pragma unroll
        for (int r = 0; r < 4; ++r)
            ma2[it][r] = floatx2{1.f, (float)la[baseRow + it * 16 + quad * 4 + r]};

    floatx2 rowacc[2][4] = {};      // (tot, c1) accumulated over all 8 j-tiles

    // wave-private col-partial slab: slab index = bx*4 + wave (256 slabs)
    float* colW = colPartW + (size_t)(bx * 4 + wave) * M_ROWS * 2;

    // ---- barrier-free j-loop: 8 tiles of 64 cols
    for (int jj = 0; jj < 8; ++jj) {
        const unsigned char* Bf = vB + (size_t)(jg * 8 + jj) * 16384
                                     + (size_t)lane * 16;
        floatx4 acc[2][4] = {};
        #pragma unroll
        for (int s = 0; s < 2; ++s) {
            #pragma unroll
            for (int jt = 0; jt < 4; ++jt) {
                int4 h0 = *(const int4*)(Bf + jt * 4096 + s * 2048);
                int4 h1 = *(const int4*)(Bf + jt * 4096 + s * 2048 + 1024);
                intx8 bf = intx8{h0.x, h0.y, h0.z, h0.w, h1.x, h1.y, h1.z, h1.w};
                acc[0][jt] = mfma_fp8(afr[0][s], bf, acc[0][jt]);
                acc[1][jt] = mfma_fp8(afr[1][s], bf, acc[1][jt]);
            }
        }

        // epilogue: exp2 + packed accumulate; C/D: col = l16, row = quad*4+r
        const int jbase = j0 + jj * 64;
        #pragma unroll
        for (int jt = 0; jt < 4; ++jt) {
            floatx2 mj = floatx2{1.f, (float)lv[jbase + jt * 16 + l16]};
            floatx2 ca = {};
            #pragma unroll
            for (int it = 0; it < 2; ++it) {
                #pragma unroll
                for (int r = 0; r < 4; ++r) {
                    float e = fast_exp2(acc[it][jt][r]);
                    floatx2 e2 = {e, e};
                    rowacc[it][r] = e2 * mj + rowacc[it][r];    // v_pk_fma_f32
                    ca = e2 * ma2[it][r] + ca;                  // v_pk_fma_f32
                }
            }
            // col partial: reduce over quads (register-only), quad 0 stores
            ca.x += __shfl_xor(ca.x, 16, 64); ca.y += __shfl_xor(ca.y, 16, 64);
            ca.x += __shfl_xor(ca.x, 32, 64); ca.y += __shfl_xor(ca.y, 32, 64);
            if (quad == 0)
                *(floatx2*)&colW[(size_t)(jbase + jt * 16 + l16) * 2] = ca;
        }
    }

    // ---- row partials -> LDS transpose buffer rp[row 0..127][slot = l16]
    #pragma unroll
    for (int it = 0; it < 2; ++it)
        #pragma unroll
        for (int r = 0; r < 4; ++r)
            rp[(wave * 32 + it * 16 + quad * 4 + r) * 16 + l16] = rowacc[it][r];
    __syncthreads();

    // ---- final row sums + coalesced global write
    {
        const int row = tid >> 1, h = tid & 1;      // 2 threads per row
        const float4* b4 = (const float4*)(rp + (size_t)row * 16 + h * 8);
        float4 q0 = b4[0], q1 = b4[1], q2 = b4[2], q3 = b4[3];
        floatx2 s = floatx2{q0.x, q0.y} + floatx2{q0.z, q0.w}
                  + floatx2{q1.x, q1.y} + floatx2{q1.z, q1.w}
                  + floatx2{q2.x, q2.y} + floatx2{q2.z, q2.w}
                  + floatx2{q3.x, q3.y} + floatx2{q3.z, q3.w};
        s.x += __shfl_xor(s.x, 1, 64);
        s.y += __shfl_xor(s.y, 1, 64);
        if (h == 0)
            *(floatx2*)&rowPart[((size_t)jg * M_ROWS + i0 + row) * 2] = s;
    }
}

// Kernel 3: reduce partials (16 row-slabs / 256 col-slabs), per-row/col log
// terms, then merged finalize: per-block (sum,count) -> device atomicAdd; last
// block (atomic counter) computes the final scalar. Blocks 0..31 = rows,
// 32..63 = cols. glob: [sumA, cntA, sumV, cntV, (int)counter].
__global__ __launch_bounds__(256) void reduce_kernel(
    const float* __restrict__ rowPart, const float* __restrict__ colPartW,
    const int* __restrict__ la, const int* __restrict__ lv,
    float* __restrict__ glob, float* __restrict__ out)
{
    const int bid = blockIdx.x;
    const bool aside = bid < 32;
    const int idx = (aside ? bid : bid - 32) * 256 + threadIdx.x;   // row or col index
    const float* part = aside ? rowPart : colPartW;
    const int* lab = aside ? la : lv;
    const int nslab = aside ? JGRP : 256;   // rows: 16 slabs, cols: 256 slabs

    float tot = 0.f, c1 = 0.f;
    #pragma unroll 4
    for (int b = 0; b < nslab; ++b) {
        float2 p = *(const float2*)(part + ((size_t)b * M_ROWS + idx) * 2);
        tot += p.x; c1 += p.y;
    }
    float num = lab[idx] ? c1 : 0.1f * (tot - c1);
    float lg = 0.f, cnt = 0.f;
    if (num > 0.f) { lg = logf((num + 1e-8f) / (tot + 1e-8f)); cnt = 1.f; }

    #pragma unroll
    for (int m = 1; m < 64; m <<= 1) {
        lg  += __shfl_xor(lg,  m, 64);
        cnt += __shfl_xor(cnt, m, 64);
    }
    __shared__ float red[4][2];
    const int w = threadIdx.x >> 6, ln = threadIdx.x & 63;
    if (ln == 0) { red[w][0] = lg; red[w][1] = cnt; }
    __syncthreads();
    if (threadIdx.x == 0) {
        float slg  = red[0][0] + red[1][0] + red[2][0] + red[3][0];
        float scnt = red[0][1] + red[1][1] + red[2][1] + red[3][1];
        float* base = glob + (aside ? 0 : 2);
        atomicAdd(&base[0], slg);
        atomicAdd(&base[1], scnt);
        __threadfence();
        int old = atomicAdd((int*)glob + 4, 1);
        if (old == 63) {
            __threadfence();
            float sA = atomicAdd(&glob[0], 0.f);
            float cA = atomicAdd(&glob[1], 0.f);
            float sV = atomicAdd(&glob[2], 0.f);
            float cV = atomicAdd(&glob[3], 0.f);
            float lossA = -sA / fmaxf(cA, 1.f);
            float lossV = -sV / fmaxf(cV, 1.f);
            out[0] = 0.5f * (lossA + lossV);
        }
    }
}

extern "C" void kernel_launch(void* const* d_in, const int* in_sizes, int n_in,
                              void* d_out, int out_size, void* d_ws, size_t ws_size,
                              hipStream_t stream)
{
    const float* af = (const float*)d_in[0];
    const float* vf = (const float*)d_in[1];
    const int*   la = (const int*)d_in[2];
    const int*   lv = (const int*)d_in[3];
    float* out = (float*)d_out;

    char* ws = (char*)d_ws;
    unsigned char* aB = (unsigned char*)ws;                            // 2 MiB (fp8 fragment order)
    unsigned char* vB = (unsigned char*)(ws + 2ull * 1024 * 1024);     // 2 MiB
    float* rowPart   = (float*)(ws +  4ull * 1024 * 1024);             // 1 MiB [16][8192][2]
    float* colPartW  = (float*)(ws +  8ull * 1024 * 1024);             // 16 MiB [256][8192][2]
    float* glob      = (float*)(ws + 24ull * 1024 * 1024);             // 4 floats + counter

    normalize_kernel<<<1024, 256, 0, stream>>>(af, vf, aB, vB, glob);
    gemm_loss_kernel<<<NJOBS, 256, 0, stream>>>(aB, vB, la, lv, rowPart, colPartW);
    reduce_kernel<<<64, 256, 0, stream>>>(rowPart, colPartW, la, lv, glob, out);
}

// Round 11
// 114.414 us; speedup vs baseline: 2.2353x; 1.1304x over previous
//
#include <hip/hip_runtime.h>

// Problem constants (B=32, N=256, D=256 -> M=8192)
#define M_ROWS 8192
#define D_DIM  256
#define BM     256                // block tile rows (i / audio)
#define BN     128                // block tile cols (j / visual)
#define NBI    (M_ROWS / BM)      // 32 i-tiles
#define NBJ    (M_ROWS / BN)      // 64 j-tiles
#define NJOBS  (NBI * NBJ)        // 2048 gemm blocks

// Fold 1/TEMP * log2(e) into normalization: acc = log2(e)*sim/TEMP, e = exp2(acc)
#define ALPHA  4.53982478f        // sqrt(log2(e)/0.07)

// fp8 fragment layout for mfma_scale_f32_16x16x128_f8f6f4 (K=128 per MFMA):
//   tile16 = 16 rows x 256 k = 4 KB, at tile*4096
//   per k-step s (0/1, K=128 each): 2 KB chunk at +s*2048
//   within chunk: half h (0/1) at +h*1024, then lane*16 bytes
//   lane l holds row (l&15), k = s*128 + (l>>4)*32 + h*16 + byte(0..15)
// => every load/store/ds op is 64 lanes x 16 B fully contiguous (stride-16).

typedef __attribute__((ext_vector_type(4))) float floatx4;  // MFMA C/D
typedef __attribute__((ext_vector_type(8))) int   intx8;    // MFMA A/B (32 B fp8)

__device__ inline float fast_exp2(float x) {
#if __has_builtin(__builtin_amdgcn_exp2f)
    return __builtin_amdgcn_exp2f(x);
#else
    return exp2f(x);
#endif
}

// MX-scaled fp8 MFMA with unit scales (E8M0 bias 127 -> 2^0). cbsz/blgp = 0 = OCP e4m3.
__device__ inline floatx4 mfma_fp8(intx8 a, intx8 b, floatx4 c) {
    return __builtin_amdgcn_mfma_scale_f32_16x16x128_f8f6f4(
        a, b, c, 0, 0, 0, 0x7f7f7f7f, 0, 0x7f7f7f7f);
}

// Kernel 1: L2-normalize, scale by ALPHA, emit fp8 e4m3 in fragment order.
// Each thread loads exactly the 16 f32 it emits (64 B contiguous); only the
// row-norm is cross-thread (2 shuffles + tiny LDS). Output store = dst + t*16,
// fully coalesced. Block 0 zeroes the finalize accumulators.
__global__ __launch_bounds__(256) void normalize_kernel(
    const float* __restrict__ af, const float* __restrict__ vf,
    unsigned char* __restrict__ aB, unsigned char* __restrict__ vB,
    float* __restrict__ glob)
{
    __shared__ float ssb[16][4];

    if (blockIdx.x == 0) {
        if (threadIdx.x < 4) glob[threadIdx.x] = 0.f;
        if (threadIdx.x == 4) ((int*)glob)[4] = 0;
    }

    const int b = blockIdx.x;            // 0..1023
    const bool isA = b < 512;
    const int T = isA ? b : b - 512;     // tile16 index 0..511
    const float* src = (isA ? af : vf) + (size_t)T * 16 * D_DIM;
    unsigned char* dst = (isA ? aB : vB) + (size_t)T * 4096;

    const int t    = threadIdx.x;
    const int wave = t >> 6, lane = t & 63;
    const int row  = t & 15;             // == lane & 15
    const int kq   = (t >> 4) & 3;
    const int h    = (t >> 6) & 1;
    const int s    = t >> 7;
    const int kbase = s * 128 + kq * 32 + h * 16;

    const float* p = src + row * D_DIM + kbase;
    float4 x0 = ((const float4*)p)[0], x1 = ((const float4*)p)[1];
    float4 x2 = ((const float4*)p)[2], x3 = ((const float4*)p)[3];

    float ss = x0.x*x0.x + x0.y*x0.y + x0.z*x0.z + x0.w*x0.w
             + x1.x*x1.x + x1.y*x1.y + x1.z*x1.z + x1.w*x1.w
             + x2.x*x2.x + x2.y*x2.y + x2.z*x2.z + x2.w*x2.w
             + x3.x*x3.x + x3.y*x3.y + x3.z*x3.z + x3.w*x3.w;
    // within a wave, lanes differing in bits 4..5 are the 4 kq groups of this row
    ss += __shfl_xor(ss, 16, 64);
    ss += __shfl_xor(ss, 32, 64);
    if (lane < 16) ssb[lane][wave] = ss;
    __syncthreads();
    float tot = ssb[row][0] + ssb[row][1] + ssb[row][2] + ssb[row][3];
    float scale = ALPHA / fmaxf(sqrtf(tot), 1e-12f);

    int4 o;
    int pk;
    pk  = __builtin_amdgcn_cvt_pk_fp8_f32(x0.x*scale, x0.y*scale, 0, false);
    pk  = __builtin_amdgcn_cvt_pk_fp8_f32(x0.z*scale, x0.w*scale, pk, true);
    o.x = pk;
    pk  = __builtin_amdgcn_cvt_pk_fp8_f32(x1.x*scale, x1.y*scale, 0, false);
    pk  = __builtin_amdgcn_cvt_pk_fp8_f32(x1.z*scale, x1.w*scale, pk, true);
    o.y = pk;
    pk  = __builtin_amdgcn_cvt_pk_fp8_f32(x2.x*scale, x2.y*scale, 0, false);
    pk  = __builtin_amdgcn_cvt_pk_fp8_f32(x2.z*scale, x2.w*scale, pk, true);
    o.z = pk;
    pk  = __builtin_amdgcn_cvt_pk_fp8_f32(x3.x*scale, x3.y*scale, 0, false);
    pk  = __builtin_amdgcn_cvt_pk_fp8_f32(x3.z*scale, x3.w*scale, pk, true);
    o.w = pk;
    *(int4*)(dst + (size_t)t * 16) = o;
}

// Kernel 2: fused GEMM (acc = log2e*sim/T) via MX-scaled fp8 K=128 MFMA,
// exp2 + (total,class1) row/col sums. Block 256x128, 8 waves, wave tile 32x128.
// B tile (32 KB) staged once in LDS, shared by all 8 waves; A direct to regs.
// This exact configuration measured 113.8 us total / VGPR 84 / no scratch.
__global__ __launch_bounds__(512, 4) void gemm_loss_kernel(
    const unsigned char* __restrict__ aB, const unsigned char* __restrict__ vB,
    const int* __restrict__ la, const int* __restrict__ lv,
    float* __restrict__ rowPart, float* __restrict__ colPart)
{
    __shared__ unsigned char ldsB[32768];       // 8 tile16 x 4 KB, fragment-linear
    __shared__ float rowbuf[2 * BM];            // 2 KB
    __shared__ float colbuf[16 * BN];           // [8 waves][2][128] = 8 KB

    const int tid  = threadIdx.x;
    const int wave = tid >> 6, lane = tid & 63;
    const int quad = lane >> 4, l16 = lane & 15;

    // supertile swizzle: 8 supers x 256 inner -> 16x16 tile regions (L2 locality)
    const int super = blockIdx.x >> 8;          // 0..7
    const int inner = blockIdx.x & 255;
    const int bx = (super & 1) * 16 + (inner & 15);    // 0..31 (i-tile of 256 rows)
    const int by = (super >> 1) * 16 + (inner >> 4);   // 0..63 (j-tile of 128 cols)
    const int i0 = bx * BM, j0 = by * BN;

    // ---- stage B tile into LDS (layout == global fragment layout, stride-16)
    {
        const unsigned char* vsrc = vB + (size_t)by * 32768 + (size_t)tid * 16;
        unsigned char* ldst = ldsB + tid * 16;
        #pragma unroll
        for (int c = 0; c < 4; ++c)
            *(int4*)(ldst + c * 8192) = *(const int4*)(vsrc + c * 8192);
    }

    // ---- A fragments [it][s]: 32 B each, halves at +0 / +1024
    const unsigned char* Abase = aB + (size_t)(bx * 16 + wave * 2) * 4096
                                    + (size_t)lane * 16;
    intx8 afr[2][2];
    #pragma unroll
    for (int it = 0; it < 2; ++it) {
        #pragma unroll
        for (int s = 0; s < 2; ++s) {
            int4 h0 = *(const int4*)(Abase + it * 4096 + s * 2048);
            int4 h1 = *(const int4*)(Abase + it * 4096 + s * 2048 + 1024);
            afr[it][s] = intx8{h0.x, h0.y, h0.z, h0.w, h1.x, h1.y, h1.z, h1.w};
        }
    }

    __syncthreads();

    // ---- main loop: 2 k-steps x 8 j-tiles, 2 MFMAs per B fragment
    floatx4 acc[2][8] = {};
    const unsigned char* Bl = ldsB + lane * 16;
    #pragma unroll
    for (int s = 0; s < 2; ++s) {
        #pragma unroll
        for (int jt = 0; jt < 8; ++jt) {
            int4 h0 = *(const int4*)(Bl + jt * 4096 + s * 2048);
            int4 h1 = *(const int4*)(Bl + jt * 4096 + s * 2048 + 1024);
            intx8 bf = intx8{h0.x, h0.y, h0.z, h0.w, h1.x, h1.y, h1.z, h1.w};
            acc[0][jt] = mfma_fp8(afr[0][s], bf, acc[0][jt]);
            acc[1][jt] = mfma_fp8(afr[1][s], bf, acc[1][jt]);
        }
    }

    // ---- epilogue: exp2 + (total, class1); C/D: col = l16, row = quad*4 + r
    const int baseRow = i0 + wave * 32;
    float maf[2][4];
    #pragma unroll
    for (int it = 0; it < 2; ++it)
        #pragma unroll
        for (int r = 0; r < 4; ++r)
            maf[it][r] = (float)la[baseRow + it * 16 + quad * 4 + r];
    float mvf[8];
    #pragma unroll
    for (int jt = 0; jt < 8; ++jt)
        mvf[jt] = (float)lv[j0 + jt * 16 + l16];

    float rT[2][4] = {}, r1[2][4] = {};
    float cT[8] = {}, c1[8] = {};
    #pragma unroll
    for (int it = 0; it < 2; ++it) {
        #pragma unroll
        for (int jt = 0; jt < 8; ++jt) {
            #pragma unroll
            for (int r = 0; r < 4; ++r) {
                float e = fast_exp2(acc[it][jt][r]);
                rT[it][r] += e;
                r1[it][r] = fmaf(mvf[jt], e, r1[it][r]);
                cT[jt] += e;
                c1[jt] = fmaf(maf[it][r], e, c1[jt]);
            }
        }
    }

    // col sums: reduce over quads within wave (register-only)
    #pragma unroll
    for (int jt = 0; jt < 8; ++jt) {
        float t0 = cT[jt], t1 = c1[jt];
        t0 += __shfl_xor(t0, 16, 64); t0 += __shfl_xor(t0, 32, 64);
        t1 += __shfl_xor(t1, 16, 64); t1 += __shfl_xor(t1, 32, 64);
        cT[jt] = t0; c1[jt] = t1;
    }

    // row sums: reduce over the quad's 16 lanes (cols), stage in LDS
    #pragma unroll
    for (int it = 0; it < 2; ++it) {
        #pragma unroll
        for (int r = 0; r < 4; ++r) {
            float s0 = rT[it][r], s1 = r1[it][r];
            #pragma unroll
            for (int m = 1; m < 16; m <<= 1) {
                s0 += __shfl_xor(s0, m, 64);
                s1 += __shfl_xor(s1, m, 64);
            }
            if (l16 == 0) {
                int rl = wave * 32 + it * 16 + quad * 4 + r;   // 0..255
                rowbuf[rl * 2 + 0] = s0;
                rowbuf[rl * 2 + 1] = s1;
            }
        }
    }
    if (quad == 0) {
        #pragma unroll
        for (int jt = 0; jt < 8; ++jt) {
            colbuf[(wave * 2 + 0) * BN + jt * 16 + l16] = cT[jt];
            colbuf[(wave * 2 + 1) * BN + jt * 16 + l16] = c1[jt];
        }
    }
    __syncthreads();

    // coalesced per-block partial writes
    {
        const int rl  = tid >> 1;      // 0..255
        const int cls = tid & 1;
        rowPart[((size_t)by * M_ROWS + i0 + rl) * 2 + cls] = rowbuf[rl * 2 + cls];
        if (tid < 256) {
            const int cl = tid >> 1;   // 0..127
            float s = 0.f;
            #pragma unroll
            for (int w = 0; w < 8; ++w)
                s += colbuf[(w * 2 + cls) * BN + cl];
            colPart[((size_t)bx * M_ROWS + j0 + cl) * 2 + cls] = s;
        }
    }
}

// Kernel 3: reduce partials (64 row-slabs / 32 col-slabs), per-row/col log
// terms, then merged finalize: per-block (sum,count) -> device atomicAdd; last
// block (atomic counter) computes the final scalar. Blocks 0..31 = rows,
// 32..63 = cols. glob: [sumA, cntA, sumV, cntV, (int)counter].
__global__ __launch_bounds__(256) void reduce_kernel(
    const float* __restrict__ rowPart, const float* __restrict__ colPart,
    const int* __restrict__ la, const int* __restrict__ lv,
    float* __restrict__ glob, float* __restrict__ out)
{
    const int bid = blockIdx.x;
    const bool aside = bid < 32;
    const int idx = (aside ? bid : bid - 32) * 256 + threadIdx.x;   // row or col index
    const float* part = aside ? rowPart : colPart;
    const int* lab = aside ? la : lv;
    const int nslab = aside ? 64 : 32;

    float tot = 0.f, c1 = 0.f;
    #pragma unroll 4
    for (int b = 0; b < nslab; ++b) {
        float2 p = *(const float2*)(part + ((size_t)b * M_ROWS + idx) * 2);
        tot += p.x; c1 += p.y;
    }
    float num = lab[idx] ? c1 : 0.1f * (tot - c1);
    float lg = 0.f, cnt = 0.f;
    if (num > 0.f) { lg = logf((num + 1e-8f) / (tot + 1e-8f)); cnt = 1.f; }

    #pragma unroll
    for (int m = 1; m < 64; m <<= 1) {
        lg  += __shfl_xor(lg,  m, 64);
        cnt += __shfl_xor(cnt, m, 64);
    }
    __shared__ float red[4][2];
    const int w = threadIdx.x >> 6, ln = threadIdx.x & 63;
    if (ln == 0) { red[w][0] = lg; red[w][1] = cnt; }
    __syncthreads();
    if (threadIdx.x == 0) {
        float slg  = red[0][0] + red[1][0] + red[2][0] + red[3][0];
        float scnt = red[0][1] + red[1][1] + red[2][1] + red[3][1];
        float* base = glob + (aside ? 0 : 2);
        atomicAdd(&base[0], slg);
        atomicAdd(&base[1], scnt);
        __threadfence();
        int old = atomicAdd((int*)glob + 4, 1);
        if (old == 63) {
            __threadfence();
            float sA = atomicAdd(&glob[0], 0.f);
            float cA = atomicAdd(&glob[1], 0.f);
            float sV = atomicAdd(&glob[2], 0.f);
            float cV = atomicAdd(&glob[3], 0.f);
            float lossA = -sA / fmaxf(cA, 1.f);
            float lossV = -sV / fmaxf(cV, 1.f);
            out[0] = 0.5f * (lossA + lossV);
        }
    }
}

extern "C" void kernel_launch(void* const* d_in, const int* in_sizes, int n_in,
                              void* d_out, int out_size, void* d_ws, size_t ws_size,
                              hipStream_t stream)
{
    const float* af = (const float*)d_in[0];
    const float* vf = (const float*)d_in[1];
    const int*   la = (const int*)d_in[2];
    const int*   lv = (const int*)d_in[3];
    float* out = (float*)d_out;

    char* ws = (char*)d_ws;
    unsigned char* aB = (unsigned char*)ws;                            // 2 MiB (fp8 fragment order)
    unsigned char* vB = (unsigned char*)(ws + 2ull * 1024 * 1024);     // 2 MiB
    float* rowPart   = (float*)(ws +  4ull * 1024 * 1024);             // 4 MiB [64][8192][2]
    float* colPart   = (float*)(ws +  8ull * 1024 * 1024);             // 2 MiB [32][8192][2]
    float* glob      = (float*)(ws + 12ull * 1024 * 1024);             // 4 floats + counter

    normalize_kernel<<<1024, 256, 0, stream>>>(af, vf, aB, vB, glob);
    gemm_loss_kernel<<<NJOBS, 512, 0, stream>>>(aB, vB, la, lv, rowPart, colPart);
    reduce_kernel<<<64, 256, 0, stream>>>(rowPart, colPart, la, lv, glob, out);
}